// Round 1
// baseline (1345.885 us; speedup 1.0000x reference)
//
#include <hip/hip_runtime.h>
#include <cstddef>

// ---------------------------------------------------------------------------
// GAT 3-layer fused pipeline, fp32 correctness-first version.
// N=50000 nodes, E=300000 edges, IN_C=256, HID=64, HEADS=4, OUT_C=128.
// ---------------------------------------------------------------------------

#define WAVE 64

// ---------------- CSR build ----------------

__global__ void degree_kernel(const int* __restrict__ dst, int* __restrict__ deg, int E) {
    int e = blockIdx.x * 256 + threadIdx.x;
    if (e < E) atomicAdd(&deg[dst[e]], 1);
}

__global__ __launch_bounds__(1024) void scan_kernel(const int* __restrict__ deg,
                                                    int* __restrict__ off, int n) {
    __shared__ int wsum[16];
    __shared__ int carry_s;
    int tid = threadIdx.x, lane = tid & 63, wid = tid >> 6;
    if (tid == 0) { carry_s = 0; off[0] = 0; }
    __syncthreads();
    for (int base = 0; base < n; base += 1024) {
        int i = base + tid;
        int v = (i < n) ? deg[i] : 0;
        int s = v;
        #pragma unroll
        for (int d = 1; d < 64; d <<= 1) {
            int t = __shfl_up(s, d, 64);
            if (lane >= d) s += t;
        }
        if (lane == 63) wsum[wid] = s;
        __syncthreads();
        if (wid == 0) {
            int wv = (lane < 16) ? wsum[lane] : 0;
            #pragma unroll
            for (int d = 1; d < 16; d <<= 1) {
                int t = __shfl_up(wv, d, 64);
                if (lane >= d) wv += t;
            }
            if (lane < 16) wsum[lane] = wv;
        }
        __syncthreads();
        int prev = (wid > 0) ? wsum[wid - 1] : 0;
        int inc = carry_s + prev + s;
        if (i < n) off[i + 1] = inc;
        int chunk_total = wsum[15];
        __syncthreads();
        if (tid == 0) carry_s += chunk_total;
        __syncthreads();
    }
}

__global__ void scatter_kernel(const int* __restrict__ src, const int* __restrict__ dst,
                               const int* __restrict__ off, int* __restrict__ cursor,
                               int* __restrict__ csrc, int E) {
    int e = blockIdx.x * 256 + threadIdx.x;
    if (e < E) {
        int d = dst[e];
        int p = off[d] + atomicAdd(&cursor[d], 1);
        csrc[p] = src[e];
    }
}

// ---------------- fp32 tiled GEMM: C = A[MxK] * B[KxN] (+bias) ----------------
// BM=128, BN=64, BK=16, 256 threads, 8x4 per thread.

__global__ __launch_bounds__(256) void gemm_kernel(
    const float* __restrict__ A, const float* __restrict__ B,
    float* __restrict__ C, const float* __restrict__ bias,
    int M, int N, int K)
{
    __shared__ float As[16][128 + 4];  // padded: write conflicts <=2-way (free)
    __shared__ float Bs[16][64];
    int tid = threadIdx.x;
    int bm = blockIdx.x * 128;
    int bn = blockIdx.y * 64;
    int tr = tid >> 4;   // 0..15 -> rows tr*8 .. tr*8+7
    int tc = tid & 15;   // cols tc*4 .. tc*4+3
    float acc[8][4] = {};

    for (int k0 = 0; k0 < K; k0 += 16) {
        #pragma unroll
        for (int t = 0; t < 2; t++) {
            int idx = tid + t * 256;       // 512 float4 loads for the A tile
            int row = idx >> 2, kq = idx & 3;
            int grow = bm + row;
            float4 a4 = make_float4(0.f, 0.f, 0.f, 0.f);
            if (grow < M) a4 = *(const float4*)(A + (size_t)grow * K + k0 + kq * 4);
            As[kq * 4 + 0][row] = a4.x;
            As[kq * 4 + 1][row] = a4.y;
            As[kq * 4 + 2][row] = a4.z;
            As[kq * 4 + 3][row] = a4.w;
        }
        {
            int kr = tid >> 4, n4 = (tid & 15) * 4;  // 256 float4 loads for B tile
            int gcol = bn + n4;
            float4 b4 = make_float4(0.f, 0.f, 0.f, 0.f);
            if (gcol < N) b4 = *(const float4*)(B + (size_t)(k0 + kr) * N + gcol);
            Bs[kr][n4 + 0] = b4.x;
            Bs[kr][n4 + 1] = b4.y;
            Bs[kr][n4 + 2] = b4.z;
            Bs[kr][n4 + 3] = b4.w;
        }
        __syncthreads();
        #pragma unroll
        for (int kk = 0; kk < 16; kk++) {
            float a[8], b[4];
            #pragma unroll
            for (int i = 0; i < 8; i++) a[i] = As[kk][tr * 8 + i];
            #pragma unroll
            for (int j = 0; j < 4; j++) b[j] = Bs[kk][tc * 4 + j];
            #pragma unroll
            for (int i = 0; i < 8; i++)
                #pragma unroll
                for (int j = 0; j < 4; j++)
                    acc[i][j] += a[i] * b[j];
        }
        __syncthreads();
    }

    #pragma unroll
    for (int i = 0; i < 8; i++) {
        int row = bm + tr * 8 + i;
        if (row >= M) continue;
        #pragma unroll
        for (int j = 0; j < 4; j++) {
            int col = bn + tc * 4 + j;
            if (col < N) {
                float v = acc[i][j];
                if (bias) v += bias[col];
                C[(size_t)row * N + col] = v;
            }
        }
    }
}

// ---------------- attention scalars: a_src/a_dst [N,4] ----------------
// one block (4 waves) per node; wave w handles head w; lane strides channels.

__global__ __launch_bounds__(256) void att_kernel(
    const float* __restrict__ h, const float* __restrict__ att_s,
    const float* __restrict__ att_d, float* __restrict__ asrc,
    float* __restrict__ adst, int n, int C)
{
    int node = blockIdx.x;
    if (node >= n) return;
    int wid = threadIdx.x >> 6, lane = threadIdx.x & 63;
    const float* hp = h + (size_t)node * 4 * C + wid * C;
    float ps = 0.f, pd = 0.f;
    for (int c = lane; c < C; c += 64) {
        float v = hp[c];
        ps += v * att_s[wid * C + c];
        pd += v * att_d[wid * C + c];
    }
    #pragma unroll
    for (int o = 32; o > 0; o >>= 1) {
        ps += __shfl_down(ps, o, 64);
        pd += __shfl_down(pd, o, 64);
    }
    if (lane == 0) {
        asrc[node * 4 + wid] = ps;
        adst[node * 4 + wid] = pd;
    }
}

// ---------------- aggregation, layers 0/1 (C=64, H=4, concat) ----------------
// one block per dst node; thread = channel (head = tid>>6); two-pass softmax;
// fused bias + linear skip + ELU.

__global__ __launch_bounds__(256) void agg01_kernel(
    const float* __restrict__ h,     // [N,256]
    const float* __restrict__ asrc,  // [N,4]
    const float* __restrict__ adst,  // [N,4]
    const int* __restrict__ off, const int* __restrict__ csrc,
    const float* __restrict__ lin,   // [N,256] = x@lw + lb
    const float* __restrict__ bias,  // [256]
    float* __restrict__ out,         // [N,256]
    int n)
{
    int d = blockIdx.x;
    if (d >= n) return;
    int tid = threadIdx.x;
    int head = tid >> 6;
    float a_d = adst[d * 4 + head];
    int s0 = off[d], s1 = off[d + 1];

    float m = -INFINITY;
    for (int i = s0; i < s1; i++) {
        int s = csrc[i];
        float e = asrc[s * 4 + head] + a_d;
        e = (e > 0.f) ? e : 0.2f * e;
        m = fmaxf(m, e);
    }
    float denom = 0.f, acc = 0.f;
    for (int i = s0; i < s1; i++) {
        int s = csrc[i];
        float e = asrc[s * 4 + head] + a_d;
        e = (e > 0.f) ? e : 0.2f * e;
        float w = __expf(e - m);
        denom += w;
        acc += w * h[(size_t)s * 256 + tid];
    }
    float val = acc / (denom + 1e-16f);
    val += bias[tid] + lin[(size_t)d * 256 + tid];
    val = (val > 0.f) ? val : (__expf(val) - 1.f);  // ELU
    out[(size_t)d * 256 + tid] = val;
}

// ---------------- aggregation, layer 2 (C=128, H=4, mean over heads) ----------

__global__ __launch_bounds__(256) void agg2_kernel(
    const float* __restrict__ h,     // [N,512]
    const float* __restrict__ asrc, const float* __restrict__ adst,
    const int* __restrict__ off, const int* __restrict__ csrc,
    const float* __restrict__ lin,   // [N,128]
    const float* __restrict__ bias,  // [128]
    float* __restrict__ out,         // [N,128]
    int n)
{
    int d = blockIdx.x;
    if (d >= n) return;
    int tid = threadIdx.x;
    int h0 = tid >> 7;  // head of channel tid (0/1); channel tid+256 has head h0+2
    float ad_a = adst[d * 4 + h0];
    float ad_b = adst[d * 4 + h0 + 2];
    int s0 = off[d], s1 = off[d + 1];

    float ma = -INFINITY, mb = -INFINITY;
    for (int i = s0; i < s1; i++) {
        int s = csrc[i];
        float ea = asrc[s * 4 + h0] + ad_a;     ea = (ea > 0.f) ? ea : 0.2f * ea;
        float eb = asrc[s * 4 + h0 + 2] + ad_b; eb = (eb > 0.f) ? eb : 0.2f * eb;
        ma = fmaxf(ma, ea);
        mb = fmaxf(mb, eb);
    }
    float da = 0.f, db = 0.f, acca = 0.f, accb = 0.f;
    for (int i = s0; i < s1; i++) {
        int s = csrc[i];
        float ea = asrc[s * 4 + h0] + ad_a;     ea = (ea > 0.f) ? ea : 0.2f * ea;
        float eb = asrc[s * 4 + h0 + 2] + ad_b; eb = (eb > 0.f) ? eb : 0.2f * eb;
        float wa = __expf(ea - ma), wb = __expf(eb - mb);
        da += wa; db += wb;
        acca += wa * h[(size_t)s * 512 + tid];
        accb += wb * h[(size_t)s * 512 + 256 + tid];
    }
    float va = acca / (da + 1e-16f);
    float vb = accb / (db + 1e-16f);

    __shared__ float vals[512];
    vals[tid] = va;
    vals[tid + 256] = vb;
    __syncthreads();
    if (tid < 128) {
        float s = 0.25f * (vals[tid] + vals[128 + tid] + vals[256 + tid] + vals[384 + tid]);
        s += bias[tid] + lin[(size_t)d * 128 + tid];
        out[(size_t)d * 128 + tid] = s;
    }
}

// ---------------------------------------------------------------------------

extern "C" void kernel_launch(void* const* d_in, const int* in_sizes, int n_in,
                              void* d_out, int out_size, void* d_ws, size_t ws_size,
                              hipStream_t stream)
{
    const float* x   = (const float*)d_in[0];
    const int*   ei  = (const int*)d_in[1];
    const float* W0  = (const float*)d_in[2];
    const float* as0 = (const float*)d_in[3];
    const float* ad0 = (const float*)d_in[4];
    const float* b0  = (const float*)d_in[5];
    const float* lw0 = (const float*)d_in[6];
    const float* lb0 = (const float*)d_in[7];
    const float* W1  = (const float*)d_in[8];
    const float* as1 = (const float*)d_in[9];
    const float* ad1 = (const float*)d_in[10];
    const float* b1  = (const float*)d_in[11];
    const float* lw1 = (const float*)d_in[12];
    const float* lb1 = (const float*)d_in[13];
    const float* W2  = (const float*)d_in[14];
    const float* as2 = (const float*)d_in[15];
    const float* ad2 = (const float*)d_in[16];
    const float* b2  = (const float*)d_in[17];
    const float* lw2 = (const float*)d_in[18];
    const float* lb2 = (const float*)d_in[19];
    float* out = (float*)d_out;

    const int N = in_sizes[0] / 256;
    const int E = in_sizes[1] / 2;
    const int* esrc = ei;
    const int* edst = ei + E;

    // Workspace layout (~208 MB total):
    float* ws_f = (float*)d_ws;
    float* act  = ws_f;                       // N*256
    float* h    = act + (size_t)N * 256;      // N*512
    float* lin  = h + (size_t)N * 512;        // N*256
    float* asrc = lin + (size_t)N * 256;      // N*4
    float* adst = asrc + (size_t)N * 4;       // N*4
    int* deg    = (int*)(adst + (size_t)N * 4);  // N
    int* off    = deg + N;                       // N+1
    int* cursor = off + N + 1;                   // N
    int* csrc   = cursor + N;                    // E

    // ---- CSR build (edge_index is fixed, but rebuilt every launch: no statics)
    hipMemsetAsync(deg, 0, sizeof(int) * (size_t)(3 * N + 1), stream);
    int egrid = (E + 255) / 256;
    degree_kernel<<<egrid, 256, 0, stream>>>(edst, deg, E);
    scan_kernel<<<1, 1024, 0, stream>>>(deg, off, N);
    scatter_kernel<<<egrid, 256, 0, stream>>>(esrc, edst, off, cursor, csrc, E);

    int gm = (N + 127) / 128;

    // ---- layer 0: GATConv(256->64,H=4,concat) + Linear(256->256), ELU
    gemm_kernel<<<dim3(gm, 4), 256, 0, stream>>>(x, W0, h, nullptr, N, 256, 256);
    gemm_kernel<<<dim3(gm, 4), 256, 0, stream>>>(x, lw0, lin, lb0, N, 256, 256);
    att_kernel<<<N, 256, 0, stream>>>(h, as0, ad0, asrc, adst, N, 64);
    agg01_kernel<<<N, 256, 0, stream>>>(h, asrc, adst, off, csrc, lin, b0, act, N);

    // ---- layer 1
    gemm_kernel<<<dim3(gm, 4), 256, 0, stream>>>(act, W1, h, nullptr, N, 256, 256);
    gemm_kernel<<<dim3(gm, 4), 256, 0, stream>>>(act, lw1, lin, lb1, N, 256, 256);
    att_kernel<<<N, 256, 0, stream>>>(h, as1, ad1, asrc, adst, N, 64);
    agg01_kernel<<<N, 256, 0, stream>>>(h, asrc, adst, off, csrc, lin, b1, act, N);

    // ---- layer 2: GATConv(256->128,H=4,mean) + Linear(256->128), no act
    gemm_kernel<<<dim3(gm, 8), 256, 0, stream>>>(act, W2, h, nullptr, N, 512, 256);
    gemm_kernel<<<dim3(gm, 2), 256, 0, stream>>>(act, lw2, lin, lb2, N, 128, 256);
    att_kernel<<<N, 256, 0, stream>>>(h, as2, ad2, asrc, adst, N, 128);
    agg2_kernel<<<N, 256, 0, stream>>>(h, asrc, adst, off, csrc, lin, b2, out, N);
}

// Round 2
// 1039.801 us; speedup vs baseline: 1.2944x; 1.2944x over previous
//
#include <hip/hip_runtime.h>
#include <cstddef>

// ---------------------------------------------------------------------------
// GAT 3-layer pipeline. GEMMs on MFMA via bf16 hi/lo split (fp32-grade
// accuracy, 3 mfma per logical mfma). fp32 edge softmax/aggregation.
// ---------------------------------------------------------------------------

typedef __bf16 bf16x8 __attribute__((ext_vector_type(8)));
typedef float floatx4 __attribute__((ext_vector_type(4)));

__device__ __forceinline__ unsigned short bf16_rn(float f) {
    unsigned int u = __float_as_uint(f);
    u += 0x7FFF + ((u >> 16) & 1);
    return (unsigned short)(u >> 16);
}
__device__ __forceinline__ float bf16_tof(unsigned short h) {
    return __uint_as_float(((unsigned int)h) << 16);
}

// ---------------- CSR build ----------------

__global__ void degree_kernel(const int* __restrict__ dst, int* __restrict__ deg, int E) {
    int e = blockIdx.x * 256 + threadIdx.x;
    if (e < E) atomicAdd(&deg[dst[e]], 1);
}

__global__ __launch_bounds__(1024) void scan_kernel(const int* __restrict__ deg,
                                                    int* __restrict__ off, int n) {
    __shared__ int wsum[16];
    __shared__ int carry_s;
    int tid = threadIdx.x, lane = tid & 63, wid = tid >> 6;
    if (tid == 0) { carry_s = 0; off[0] = 0; }
    __syncthreads();
    for (int base = 0; base < n; base += 1024) {
        int i = base + tid;
        int v = (i < n) ? deg[i] : 0;
        int s = v;
        #pragma unroll
        for (int d = 1; d < 64; d <<= 1) {
            int t = __shfl_up(s, d, 64);
            if (lane >= d) s += t;
        }
        if (lane == 63) wsum[wid] = s;
        __syncthreads();
        if (wid == 0) {
            int wv = (lane < 16) ? wsum[lane] : 0;
            #pragma unroll
            for (int d = 1; d < 16; d <<= 1) {
                int t = __shfl_up(wv, d, 64);
                if (lane >= d) wv += t;
            }
            if (lane < 16) wsum[lane] = wv;
        }
        __syncthreads();
        int prev = (wid > 0) ? wsum[wid - 1] : 0;
        int inc = carry_s + prev + s;
        if (i < n) off[i + 1] = inc;
        int chunk_total = wsum[15];
        __syncthreads();
        if (tid == 0) carry_s += chunk_total;
        __syncthreads();
    }
}

__global__ void scatter_kernel(const int* __restrict__ src, const int* __restrict__ dst,
                               const int* __restrict__ off, int* __restrict__ cursor,
                               int* __restrict__ csrc, int E) {
    int e = blockIdx.x * 256 + threadIdx.x;
    if (e < E) {
        int d = dst[e];
        int p = off[d] + atomicAdd(&cursor[d], 1);
        csrc[p] = src[e];
    }
}

// ---------------- conversions ----------------

// fp32 [n*4] -> bf16 hi/lo split, vectorized by 4
__global__ void convert_split_kernel(const float* __restrict__ in,
                                     ushort* __restrict__ hi, ushort* __restrict__ lo,
                                     int n4) {
    int i = blockIdx.x * 256 + threadIdx.x;
    if (i >= n4) return;
    float4 v = ((const float4*)in)[i];
    ushort4 h, l;
    h.x = bf16_rn(v.x); l.x = bf16_rn(v.x - bf16_tof(h.x));
    h.y = bf16_rn(v.y); l.y = bf16_rn(v.y - bf16_tof(h.y));
    h.z = bf16_rn(v.z); l.z = bf16_rn(v.z - bf16_tof(h.z));
    h.w = bf16_rn(v.w); l.w = bf16_rn(v.w - bf16_tof(h.w));
    ((ushort4*)hi)[i] = h;
    ((ushort4*)lo)[i] = l;
}

// W fp32 [K,N] row-major -> transposed bf16 hi/lo [N,K]
__global__ void convert_w_kernel(const float* __restrict__ W,
                                 ushort* __restrict__ Th, ushort* __restrict__ Tl,
                                 int K, int N) {
    int idx = blockIdx.x * 256 + threadIdx.x;
    if (idx >= K * N) return;
    int k = idx / N, n = idx - k * N;
    float v = W[idx];
    unsigned short h = bf16_rn(v);
    Th[(size_t)n * K + k] = h;
    Tl[(size_t)n * K + k] = bf16_rn(v - bf16_tof(h));
}

// ---------------- MFMA GEMM: C = A[MxK] * B[KxN] (+bias) --------------------
// A as bf16 hi/lo [M,K]; B pre-transposed bf16 hi/lo [N,K].
// BM=128, BN=128, BK=32; 256 threads = 4 waves, each wave 64x64.
// Output: fp32 (Cf) or bf16 (Cb). N must be a multiple of 128, K of 32.

#define LDS_STRIDE 40  // ushorts per row: 32 data + 8 pad (80 B) -> frag reads <=2-way

__global__ __launch_bounds__(256) void gemm_mfma_kernel(
    const ushort* __restrict__ Ah, const ushort* __restrict__ Al,
    const ushort* __restrict__ Bh, const ushort* __restrict__ Bl,
    float* __restrict__ Cf, ushort* __restrict__ Cb, const float* __restrict__ bias,
    int M, int N, int K)
{
    __shared__ ushort lds[4 * 128 * LDS_STRIDE];
    const int AH = 0, AL = 128 * LDS_STRIDE, BH = 2 * 128 * LDS_STRIDE, BL = 3 * 128 * LDS_STRIDE;

    int tid = threadIdx.x;
    int bm = blockIdx.x * 128;
    int bn = blockIdx.y * 128;
    int lane = tid & 63, wid = tid >> 6;
    int wm = (wid >> 1) * 64;   // wave row offset in tile
    int wn = (wid & 1) * 64;    // wave col offset in tile
    int fr = lane & 15;         // fragment row/col index
    int q  = lane >> 4;         // quad (k-chunk / acc row group)

    floatx4 acc[4][4] = {};

    for (int k0 = 0; k0 < K; k0 += 32) {
        __syncthreads();
        #pragma unroll
        for (int t = 0; t < 2; ++t) {
            int idx = tid + t * 256;          // 512 chunks of 16B per buffer
            int row = idx >> 2, c = idx & 3;
            size_t goff = (size_t)(bm + row) * K + k0 + c * 8;
            float4 va = make_float4(0.f, 0.f, 0.f, 0.f), vl = va;
            if (bm + row < M) {
                va = *(const float4*)(Ah + goff);
                vl = *(const float4*)(Al + goff);
            }
            *(float4*)(&lds[AH + row * LDS_STRIDE + c * 8]) = va;
            *(float4*)(&lds[AL + row * LDS_STRIDE + c * 8]) = vl;
            size_t boff = (size_t)(bn + row) * K + k0 + c * 8;
            *(float4*)(&lds[BH + row * LDS_STRIDE + c * 8]) = *(const float4*)(Bh + boff);
            *(float4*)(&lds[BL + row * LDS_STRIDE + c * 8]) = *(const float4*)(Bl + boff);
        }
        __syncthreads();

        bf16x8 ah[4], al[4], bh[4], bl[4];
        #pragma unroll
        for (int i = 0; i < 4; ++i) {
            int r = wm + i * 16 + fr;
            ah[i] = *(const bf16x8*)(&lds[AH + r * LDS_STRIDE + q * 8]);
            al[i] = *(const bf16x8*)(&lds[AL + r * LDS_STRIDE + q * 8]);
        }
        #pragma unroll
        for (int j = 0; j < 4; ++j) {
            int r = wn + j * 16 + fr;
            bh[j] = *(const bf16x8*)(&lds[BH + r * LDS_STRIDE + q * 8]);
            bl[j] = *(const bf16x8*)(&lds[BL + r * LDS_STRIDE + q * 8]);
        }
        #pragma unroll
        for (int i = 0; i < 4; ++i)
            #pragma unroll
            for (int j = 0; j < 4; ++j) {
                acc[i][j] = __builtin_amdgcn_mfma_f32_16x16x32_bf16(ah[i], bh[j], acc[i][j], 0, 0, 0);
                acc[i][j] = __builtin_amdgcn_mfma_f32_16x16x32_bf16(ah[i], bl[j], acc[i][j], 0, 0, 0);
                acc[i][j] = __builtin_amdgcn_mfma_f32_16x16x32_bf16(al[i], bh[j], acc[i][j], 0, 0, 0);
            }
    }

    // C/D layout: col = lane&15, row = (lane>>4)*4 + reg  (verified m89/m91)
    #pragma unroll
    for (int i = 0; i < 4; ++i) {
        #pragma unroll
        for (int r = 0; r < 4; ++r) {
            int grow = bm + wm + i * 16 + q * 4 + r;
            if (grow < M) {
                #pragma unroll
                for (int j = 0; j < 4; ++j) {
                    int gcol = bn + wn + j * 16 + fr;
                    float v = acc[i][j][r];
                    if (bias) v += bias[gcol];
                    if (Cf) Cf[(size_t)grow * N + gcol] = v;
                    else    Cb[(size_t)grow * N + gcol] = bf16_rn(v);
                }
            }
        }
    }
}

// ---------------- attention scalars: a_src/a_dst [N,4] ----------------

__global__ __launch_bounds__(256) void att_kernel(
    const float* __restrict__ h, const float* __restrict__ att_s,
    const float* __restrict__ att_d, float* __restrict__ asrc,
    float* __restrict__ adst, int n, int C)
{
    int node = blockIdx.x;
    if (node >= n) return;
    int wid = threadIdx.x >> 6, lane = threadIdx.x & 63;
    const float* hp = h + (size_t)node * 4 * C + wid * C;
    float ps = 0.f, pd = 0.f;
    for (int c = lane; c < C; c += 64) {
        float v = hp[c];
        ps += v * att_s[wid * C + c];
        pd += v * att_d[wid * C + c];
    }
    #pragma unroll
    for (int o = 32; o > 0; o >>= 1) {
        ps += __shfl_down(ps, o, 64);
        pd += __shfl_down(pd, o, 64);
    }
    if (lane == 0) {
        asrc[node * 4 + wid] = ps;
        adst[node * 4 + wid] = pd;
    }
}

// ---------------- aggregation layers 0/1: out = bf16 hi/lo split -------------

__global__ __launch_bounds__(256) void agg01_kernel(
    const float* __restrict__ h,     // [N,256]
    const float* __restrict__ asrc, const float* __restrict__ adst,
    const int* __restrict__ off, const int* __restrict__ csrc,
    const ushort* __restrict__ lin,  // [N,256] bf16
    const float* __restrict__ bias,  // [256]
    ushort* __restrict__ out_hi, ushort* __restrict__ out_lo,
    int n)
{
    int d = blockIdx.x;
    if (d >= n) return;
    int tid = threadIdx.x;
    int head = tid >> 6;
    float a_d = adst[d * 4 + head];
    int s0 = off[d], s1 = off[d + 1];

    float m = -INFINITY;
    for (int i = s0; i < s1; i++) {
        int s = csrc[i];
        float e = asrc[s * 4 + head] + a_d;
        e = (e > 0.f) ? e : 0.2f * e;
        m = fmaxf(m, e);
    }
    float denom = 0.f, acc = 0.f;
    for (int i = s0; i < s1; i++) {
        int s = csrc[i];
        float e = asrc[s * 4 + head] + a_d;
        e = (e > 0.f) ? e : 0.2f * e;
        float w = __expf(e - m);
        denom += w;
        acc += w * h[(size_t)s * 256 + tid];
    }
    float val = acc / (denom + 1e-16f);
    val += bias[tid] + bf16_tof(lin[(size_t)d * 256 + tid]);
    val = (val > 0.f) ? val : (__expf(val) - 1.f);  // ELU
    unsigned short hv = bf16_rn(val);
    out_hi[(size_t)d * 256 + tid] = hv;
    out_lo[(size_t)d * 256 + tid] = bf16_rn(val - bf16_tof(hv));
}

// ---------------- aggregation layer 2: mean over heads, fp32 out -------------

__global__ __launch_bounds__(256) void agg2_kernel(
    const float* __restrict__ h,     // [N,512]
    const float* __restrict__ asrc, const float* __restrict__ adst,
    const int* __restrict__ off, const int* __restrict__ csrc,
    const ushort* __restrict__ lin,  // [N,128] bf16
    const float* __restrict__ bias,  // [128]
    float* __restrict__ out,         // [N,128]
    int n)
{
    int d = blockIdx.x;
    if (d >= n) return;
    int tid = threadIdx.x;
    int h0 = tid >> 7;
    float ad_a = adst[d * 4 + h0];
    float ad_b = adst[d * 4 + h0 + 2];
    int s0 = off[d], s1 = off[d + 1];

    float ma = -INFINITY, mb = -INFINITY;
    for (int i = s0; i < s1; i++) {
        int s = csrc[i];
        float ea = asrc[s * 4 + h0] + ad_a;     ea = (ea > 0.f) ? ea : 0.2f * ea;
        float eb = asrc[s * 4 + h0 + 2] + ad_b; eb = (eb > 0.f) ? eb : 0.2f * eb;
        ma = fmaxf(ma, ea);
        mb = fmaxf(mb, eb);
    }
    float da = 0.f, db = 0.f, acca = 0.f, accb = 0.f;
    for (int i = s0; i < s1; i++) {
        int s = csrc[i];
        float ea = asrc[s * 4 + h0] + ad_a;     ea = (ea > 0.f) ? ea : 0.2f * ea;
        float eb = asrc[s * 4 + h0 + 2] + ad_b; eb = (eb > 0.f) ? eb : 0.2f * eb;
        float wa = __expf(ea - ma), wb = __expf(eb - mb);
        da += wa; db += wb;
        acca += wa * h[(size_t)s * 512 + tid];
        accb += wb * h[(size_t)s * 512 + 256 + tid];
    }
    float va = acca / (da + 1e-16f);
    float vb = accb / (db + 1e-16f);

    __shared__ float vals[512];
    vals[tid] = va;
    vals[tid + 256] = vb;
    __syncthreads();
    if (tid < 128) {
        float s = 0.25f * (vals[tid] + vals[128 + tid] + vals[256 + tid] + vals[384 + tid]);
        s += bias[tid] + bf16_tof(lin[(size_t)d * 128 + tid]);
        out[(size_t)d * 128 + tid] = s;
    }
}

// ---------------------------------------------------------------------------

extern "C" void kernel_launch(void* const* d_in, const int* in_sizes, int n_in,
                              void* d_out, int out_size, void* d_ws, size_t ws_size,
                              hipStream_t stream)
{
    const float* x   = (const float*)d_in[0];
    const int*   ei  = (const int*)d_in[1];
    const float* W0  = (const float*)d_in[2];
    const float* as0 = (const float*)d_in[3];
    const float* ad0 = (const float*)d_in[4];
    const float* b0  = (const float*)d_in[5];
    const float* lw0 = (const float*)d_in[6];
    const float* lb0 = (const float*)d_in[7];
    const float* W1  = (const float*)d_in[8];
    const float* as1 = (const float*)d_in[9];
    const float* ad1 = (const float*)d_in[10];
    const float* b1  = (const float*)d_in[11];
    const float* lw1 = (const float*)d_in[12];
    const float* lb1 = (const float*)d_in[13];
    const float* W2  = (const float*)d_in[14];
    const float* as2 = (const float*)d_in[15];
    const float* ad2 = (const float*)d_in[16];
    const float* b2  = (const float*)d_in[17];
    const float* lw2 = (const float*)d_in[18];
    const float* lb2 = (const float*)d_in[19];
    float* out = (float*)d_out;

    const int N = in_sizes[0] / 256;
    const int E = in_sizes[1] / 2;
    const int* esrc = ei;
    const int* edst = ei + E;

    // ---- workspace layout (~184 MB) ----
    char* p = (char*)d_ws;
    ushort* act_hi = (ushort*)p; p += (size_t)N * 256 * 2;   // 25.6 MB
    ushort* act_lo = (ushort*)p; p += (size_t)N * 256 * 2;   // 25.6 MB
    float*  h      = (float*)p;  p += (size_t)N * 512 * 4;   // 102.4 MB
    ushort* lin    = (ushort*)p; p += (size_t)N * 256 * 2;   // 25.6 MB (bf16)
    float*  asrc   = (float*)p;  p += (size_t)N * 4 * 4;
    float*  adst   = (float*)p;  p += (size_t)N * 4 * 4;
    ushort* w0t_h  = (ushort*)p; p += 256 * 256 * 2;
    ushort* w0t_l  = (ushort*)p; p += 256 * 256 * 2;
    ushort* l0t_h  = (ushort*)p; p += 256 * 256 * 2;
    ushort* l0t_l  = (ushort*)p; p += 256 * 256 * 2;
    ushort* w1t_h  = (ushort*)p; p += 256 * 256 * 2;
    ushort* w1t_l  = (ushort*)p; p += 256 * 256 * 2;
    ushort* l1t_h  = (ushort*)p; p += 256 * 256 * 2;
    ushort* l1t_l  = (ushort*)p; p += 256 * 256 * 2;
    ushort* w2t_h  = (ushort*)p; p += 512 * 256 * 2;
    ushort* w2t_l  = (ushort*)p; p += 512 * 256 * 2;
    ushort* l2t_h  = (ushort*)p; p += 128 * 256 * 2;
    ushort* l2t_l  = (ushort*)p; p += 128 * 256 * 2;
    int* deg    = (int*)p;
    int* off    = deg + N;
    int* cursor = off + N + 1;
    int* csrc   = cursor + N;

    // ---- CSR build ----
    hipMemsetAsync(deg, 0, sizeof(int) * (size_t)(3 * N + 1), stream);
    int egrid = (E + 255) / 256;
    degree_kernel<<<egrid, 256, 0, stream>>>(edst, deg, E);
    scan_kernel<<<1, 1024, 0, stream>>>(deg, off, N);
    scatter_kernel<<<egrid, 256, 0, stream>>>(esrc, edst, off, cursor, csrc, E);

    // ---- weight conversions (tiny) ----
    int wg64k = (256 * 256 + 255) / 256;
    convert_w_kernel<<<wg64k, 256, 0, stream>>>(W0,  w0t_h, w0t_l, 256, 256);
    convert_w_kernel<<<wg64k, 256, 0, stream>>>(lw0, l0t_h, l0t_l, 256, 256);
    convert_w_kernel<<<wg64k, 256, 0, stream>>>(W1,  w1t_h, w1t_l, 256, 256);
    convert_w_kernel<<<wg64k, 256, 0, stream>>>(lw1, l1t_h, l1t_l, 256, 256);
    convert_w_kernel<<<2 * wg64k, 256, 0, stream>>>(W2,  w2t_h, w2t_l, 256, 512);
    convert_w_kernel<<<(256 * 128 + 255) / 256, 256, 0, stream>>>(lw2, l2t_h, l2t_l, 256, 128);

    // ---- x -> bf16 hi/lo ----
    int n4 = N * 256 / 4;
    convert_split_kernel<<<(n4 + 255) / 256, 256, 0, stream>>>(x, act_hi, act_lo, n4);

    int gm = (N + 127) / 128;

    // ---- layer 0 ----
    gemm_mfma_kernel<<<dim3(gm, 2), 256, 0, stream>>>(act_hi, act_lo, w0t_h, w0t_l, h, nullptr, nullptr, N, 256, 256);
    gemm_mfma_kernel<<<dim3(gm, 2), 256, 0, stream>>>(act_hi, act_lo, l0t_h, l0t_l, nullptr, lin, lb0, N, 256, 256);
    att_kernel<<<N, 256, 0, stream>>>(h, as0, ad0, asrc, adst, N, 64);
    agg01_kernel<<<N, 256, 0, stream>>>(h, asrc, adst, off, csrc, lin, b0, act_hi, act_lo, N);

    // ---- layer 1 ----
    gemm_mfma_kernel<<<dim3(gm, 2), 256, 0, stream>>>(act_hi, act_lo, w1t_h, w1t_l, h, nullptr, nullptr, N, 256, 256);
    gemm_mfma_kernel<<<dim3(gm, 2), 256, 0, stream>>>(act_hi, act_lo, l1t_h, l1t_l, nullptr, lin, lb1, N, 256, 256);
    att_kernel<<<N, 256, 0, stream>>>(h, as1, ad1, asrc, adst, N, 64);
    agg01_kernel<<<N, 256, 0, stream>>>(h, asrc, adst, off, csrc, lin, b1, act_hi, act_lo, N);

    // ---- layer 2 ----
    gemm_mfma_kernel<<<dim3(gm, 4), 256, 0, stream>>>(act_hi, act_lo, w2t_h, w2t_l, h, nullptr, nullptr, N, 512, 256);
    gemm_mfma_kernel<<<dim3(gm, 1), 256, 0, stream>>>(act_hi, act_lo, l2t_h, l2t_l, nullptr, lin, lb2, N, 128, 256);
    att_kernel<<<N, 256, 0, stream>>>(h, as2, ad2, asrc, adst, N, 128);
    agg2_kernel<<<N, 256, 0, stream>>>(h, asrc, adst, off, csrc, lin, b2, out, N);
}